// Round 1
// baseline (690.941 us; speedup 1.0000x reference)
//
#include <hip/hip_runtime.h>
#include <hip/hip_fp16.h>

// DeductronCTC: logits = (scan of affine maps from two sigmoid GEMMs) @ W_logit + b
// Pipeline: K0 transpose W_logit; K1 compute a,b (fp16, packed into d_out);
//           K2 chunk summaries; K3 scan summaries; K4 apply + logits GEMM.
// a,b live inside d_out rows (a_t|b_t = 256B = the same bytes row t's logits
// later occupy; K4 reads its own rows before overwriting them -> no race).
// ws usage: ~6 MB (W_logit^T + chunk summaries + chunk start states).

constexpr int NF  = 500000;   // N_FRAMES
constexpr int KIN = 128;      // INPUT_LEN
constexpr int M   = 64;       // N_MEMORY == N_CLASSES
constexpr int CH  = 64;       // rows per scan chunk (= K4 block tile)
constexpr int NC  = (NF + CH - 1) / CH;   // 7813 chunks

__device__ __forceinline__ float sig(float x) { return 1.0f / (1.0f + __expf(-x)); }

// ---------------------------------------------------------------- K0
__global__ void k0_transpose(const float* __restrict__ W, float* __restrict__ WT) {
    int idx = blockIdx.x * 256 + threadIdx.x;
    if (idx < M * M) {
        int j = idx >> 6, k = idx & 63;
        WT[j * M + k] = W[k * M + j];   // WT[class][mem]
    }
}

// ---------------------------------------------------------------- K1
// left = sig(X@WL+bL), right = sig(X@WR+bR); a=left*right, b=1-left (fp16).
// W staged in LDS as packed half2 (WL,WR); 8-row register blocking per wave.
__global__ __launch_bounds__(256, 2)
void k1_gemm_ab(const float* __restrict__ X,
                const float* __restrict__ WL, const float* __restrict__ bL,
                const float* __restrict__ WR, const float* __restrict__ bR,
                __half* __restrict__ ab)
{
    __shared__ __half2 w_s[KIN * M];    // 32 KiB: (WL,WR) pairs, layout [k][j]
    __shared__ float   x_s[4][8 * KIN]; // 16 KiB: per-wave 8-row X tile

    const int tid = threadIdx.x;
    for (int i = tid; i < KIN * M; i += 256)
        w_s[i] = __halves2half2(__float2half(WL[i]), __float2half(WR[i]));
    __syncthreads();

    const int lane = tid & 63;
    const int w    = tid >> 6;
    const float blv = bL[lane];
    const float brv = bR[lane];
    const int row_base = blockIdx.x * 256;

    for (int it = 0; it < 8; ++it) {
        const int r0 = row_base + it * 32 + w * 8;

        // stage 8 rows of X (coalesced); x_s[w] is wave-private, lgkmcnt orders it
        #pragma unroll
        for (int e = 0; e < 16; ++e) {
            int idx = e * 64 + lane;
            int r = idx >> 7;
            int k = idx & 127;
            int row = r0 + r;
            x_s[w][r * KIN + k] = (row < NF) ? X[row * KIN + k] : 0.0f;
        }

        float accL[8], accR[8];
        #pragma unroll
        for (int r = 0; r < 8; ++r) { accL[r] = blv; accR[r] = brv; }

        #pragma unroll 4
        for (int k = 0; k < KIN; ++k) {
            float2 wv = __half22float2(w_s[k * M + lane]);   // 1 LDS b32, conflict-free
            #pragma unroll
            for (int r = 0; r < 8; ++r) {
                float xv = x_s[w][r * KIN + k];              // broadcast reads
                accL[r] = fmaf(xv, wv.x, accL[r]);
                accR[r] = fmaf(xv, wv.y, accR[r]);
            }
        }

        #pragma unroll
        for (int r = 0; r < 8; ++r) {
            int row = r0 + r;
            if (row < NF) {
                float l  = sig(accL[r]);
                float rr = sig(accR[r]);
                ab[row * 2 * M + lane]     = __float2half(l * rr);   // a
                ab[row * 2 * M + M + lane] = __float2half(1.0f - l); // b
            }
        }
    }
}

// ---------------------------------------------------------------- K2
// Per-chunk affine composition. op(first,(a,b)): A=a*A, B=a*B+b.
__global__ __launch_bounds__(64)
void k2_summary(const __half* __restrict__ ab,
                float* __restrict__ sA, float* __restrict__ sB)
{
    const int c = blockIdx.x;
    const int j = threadIdx.x;
    const int t0 = c * CH;
    const int tend = min(t0 + CH, NF - 1);   // transforms exist for t < NF-1
    float A = 1.0f, B = 0.0f;
    #pragma unroll 4
    for (int t = t0; t < tend; ++t) {
        float a = __half2float(ab[t * 2 * M + j]);
        float b = __half2float(ab[t * 2 * M + M + j]);
        B = fmaf(a, B, b);
        A *= a;
    }
    sA[j * NC + c] = A;   // transposed layout -> K3 reads coalesced
    sB[j * NC + c] = B;
}

// ---------------------------------------------------------------- K3
// Scan chunk summaries; u0[c] = state at chunk start (z[c*CH]). One wave/column.
__global__ __launch_bounds__(64)
void k3_scan(const float* __restrict__ sA, const float* __restrict__ sB,
             float* __restrict__ u0)
{
    const int j = blockIdx.x;
    const int lane = threadIdx.x;
    float cB = 0.0f;                       // carry applied to u=0 -> only B needed
    const int NG = (NC + 63) / 64;
    for (int g = 0; g < NG; ++g) {
        int c = g * 64 + lane;
        bool valid = c < NC;
        float A = valid ? sA[j * NC + c] : 1.0f;
        float B = valid ? sB[j * NC + c] : 0.0f;
        // Hillis-Steele inclusive scan: cur = op(prev, cur)
        #pragma unroll
        for (int d = 1; d < 64; d <<= 1) {
            float pA = __shfl_up(A, d);
            float pB = __shfl_up(B, d);
            if (lane >= d) {
                B = fmaf(A, pB, B);
                A *= pA;
            }
        }
        // exclusive + apply carry to u=0:  u_start = A_excl*cB + B_excl
        float eA = __shfl_up(A, 1);
        float eB = __shfl_up(B, 1);
        if (lane == 0) { eA = 1.0f; eB = 0.0f; }
        float uB = fmaf(eA, cB, eB);
        if (valid) u0[c * M + j] = uB;
        // fold group total into carry
        float tA = __shfl(A, 63);
        float tB = __shfl(B, 63);
        cB = fmaf(tA, cB, tB);
    }
}

// ---------------------------------------------------------------- K4
// Apply scan within chunk (column-per-lane), then logits GEMM (row-per-lane,
// z in VGPRs, W^T via wave-uniform -> scalar loads). Overwrites own a,b rows.
__global__ __launch_bounds__(64)
void k4_apply(const __half* ab, const float* __restrict__ u0,
              const float* __restrict__ WT, const float* __restrict__ bl,
              float* out)
{
    __shared__ float z_s[CH][M + 4];
    const int c  = blockIdx.x;
    const int j  = threadIdx.x;
    const int t0 = c * CH;
    const int rows = min(CH, NF - t0);

    float u = u0[c * M + j];
    for (int i = 0; i < rows; ++i) {
        z_s[i][j] = u;                       // z[t] BEFORE applying step t
        int t = t0 + i;
        if (t < NF - 1) {
            float a = __half2float(ab[t * 2 * M + j]);
            float b = __half2float(ab[t * 2 * M + M + j]);
            u = fmaf(a, u, b);
        }
    }
    __syncthreads();                          // all a,b consumed before overwrite

    if (j < rows) {
        float z[M];
        #pragma unroll
        for (int k = 0; k < M; ++k) z[k] = z_s[j][k];
        const int t = t0 + j;
        #pragma unroll 1
        for (int jg = 0; jg < 4; ++jg) {
            float o[16];
            #pragma unroll
            for (int jj = 0; jj < 16; ++jj) {
                int col = jg * 16 + jj;
                float acc = bl[col];
                #pragma unroll
                for (int k = 0; k < M; ++k)
                    acc = fmaf(z[k], WT[col * M + k], acc);   // SGPR operand
                o[jj] = acc;
            }
            float4* dst = reinterpret_cast<float4*>(&out[t * M + jg * 16]);
            dst[0] = make_float4(o[0],  o[1],  o[2],  o[3]);
            dst[1] = make_float4(o[4],  o[5],  o[6],  o[7]);
            dst[2] = make_float4(o[8],  o[9],  o[10], o[11]);
            dst[3] = make_float4(o[12], o[13], o[14], o[15]);
        }
    }
}

// ---------------------------------------------------------------- host
extern "C" void kernel_launch(void* const* d_in, const int* in_sizes, int n_in,
                              void* d_out, int out_size, void* d_ws, size_t ws_size,
                              hipStream_t stream)
{
    const float* X    = (const float*)d_in[0];
    // d_in[1] = targets (unused by reference output)
    const float* WL   = (const float*)d_in[2];
    const float* bL   = (const float*)d_in[3];
    const float* WR   = (const float*)d_in[4];
    const float* bR   = (const float*)d_in[5];
    const float* WLog = (const float*)d_in[6];
    const float* bLog = (const float*)d_in[7];

    float* ws  = (float*)d_ws;
    float* WT  = ws;                        // 4096 floats
    float* sA  = ws + 4096;                 // 64*NC
    float* sB  = sA + 64 * NC;              // 64*NC
    float* u0  = sB + 64 * NC;              // NC*64
    // total ~6.02 MB of ws

    __half* ab = (__half*)d_out;            // a,b packed into output buffer

    k0_transpose<<<16, 256, 0, stream>>>(WLog, WT);
    k1_gemm_ab<<<(NF + 255) / 256, 256, 0, stream>>>(X, WL, bL, WR, bR, ab);
    k2_summary<<<NC, 64, 0, stream>>>(ab, sA, sB);
    k3_scan<<<64, 64, 0, stream>>>(sA, sB, u0);
    k4_apply<<<NC, 64, 0, stream>>>(ab, u0, WT, bLog, (float*)d_out);
}

// Round 3
// 526.867 us; speedup vs baseline: 1.3114x; 1.3114x over previous
//
#include <hip/hip_runtime.h>
#include <hip/hip_fp16.h>

// DeductronCTC pipeline v3 (replay-safe by construction):
//   K1: X -> fp16-MFMA [WL|WR] -> sigmoid -> a,b (LDS only) -> fused chunk
//       summary -> sA,sB (ws). No ab stored to global.
//   K3: scan of chunk summaries -> u0 (ws).
//   K4: re-stage X, recompute a,b with the IDENTICAL MFMA pipeline (bitwise
//       same values as K1), apply scan from u0, fp16-MFMA logits GEMM -> out.
// d_out is written exactly once (K4, write-only). ws = 6 MB (sA,sB,u0).
// No buffer is both read and written by any kernel; no pointer aliasing.

constexpr int NF  = 500000;   // N_FRAMES
constexpr int KIN = 128;      // INPUT_LEN
constexpr int M   = 64;       // N_MEMORY == N_CLASSES
constexpr int CH  = 64;       // rows per scan chunk
constexpr int NC  = (NF + CH - 1) / CH;   // 7813 chunks

typedef _Float16 f16x8 __attribute__((ext_vector_type(8)));
typedef _Float16 f16x4 __attribute__((ext_vector_type(4)));
typedef float    f32x4 __attribute__((ext_vector_type(4)));

__device__ __forceinline__ float sig(float x) { return 1.0f / (1.0f + __expf(-x)); }

// Shared building block: pack W=[WL|WR] into MFMA B-frag layout, stage 16 X
// rows per wave as f16, run the 16x128 MFMA per wave. Used by K1 and K4 with
// identical code so a,b values match bitwise.

// ---------------------------------------------------------------- K1
__global__ __launch_bounds__(256, 3)
void k1_summary(const float* __restrict__ X,
                const float* __restrict__ WL, const float* __restrict__ bL,
                const float* __restrict__ WR, const float* __restrict__ bR,
                float* __restrict__ sA, float* __restrict__ sB)
{
    __shared__ _Float16 wpack[16 * 128 * 8];   // 32 KiB
    __shared__ _Float16 x_s[4][16][136];       // 17 KiB
    _Float16* as_s = wpack;                        // [64][64] (reuse)
    _Float16* bs_s = wpack + 64 * 64;              // [64][64]
    float*    pA_s = (float*)(wpack + 2 * 64 * 64);// [4][64]
    float*    pB_s = pA_s + 4 * 64;                // [4][64]

    const int tid  = threadIdx.x;
    const int lane = tid & 63;
    const int w    = tid >> 6;
    const int t0   = blockIdx.x * CH;

    // pack W = [WL|WR] into fragment layout [k>>3][col][k&7]
    #pragma unroll
    for (int f = 0; f < 16; ++f) {
        int flat = f * 1024 + tid * 4;
        int k = flat >> 7, col = flat & 127;
        float4 v;
        if (col < 64) v = *(const float4*)&WL[k * 64 + col];
        else          v = *(const float4*)&WR[k * 64 + (col - 64)];
        int kb = k >> 3, kj = k & 7;
        wpack[(kb * 128 + col + 0) * 8 + kj] = (_Float16)v.x;
        wpack[(kb * 128 + col + 1) * 8 + kj] = (_Float16)v.y;
        wpack[(kb * 128 + col + 2) * 8 + kj] = (_Float16)v.z;
        wpack[(kb * 128 + col + 3) * 8 + kj] = (_Float16)v.w;
    }

    // stage this wave's 16 X rows (f32 -> f16)
    const int r0 = t0 + w * 16;
    #pragma unroll
    for (int it = 0; it < 8; ++it) {
        int flat = it * 256 + lane * 4;
        int r = flat >> 7, k = flat & 127;
        float4 v = make_float4(0.f, 0.f, 0.f, 0.f);
        if (r0 + r < NF) v = *(const float4*)&X[(r0 + r) * KIN + k];
        f16x4 h = { (_Float16)v.x, (_Float16)v.y, (_Float16)v.z, (_Float16)v.w };
        *(f16x4*)&x_s[w][r][k] = h;
    }
    __syncthreads();

    // MFMA: wave w -> rows [w*16, w*16+16) x 128 cols
    const int arow = lane & 15;
    const int kb   = lane >> 4;
    f32x4 acc[8];
    #pragma unroll
    for (int c = 0; c < 8; ++c) acc[c] = (f32x4){0.f, 0.f, 0.f, 0.f};
    #pragma unroll
    for (int s = 0; s < 4; ++s) {
        f16x8 af = *(const f16x8*)&x_s[w][arow][s * 32 + kb * 8];
        #pragma unroll
        for (int c = 0; c < 8; ++c) {
            f16x8 bf = *(const f16x8*)&wpack[((s * 4 + kb) * 128 + c * 16 + arow) * 8];
            acc[c] = __builtin_amdgcn_mfma_f32_16x16x32_f16(af, bf, acc[c], 0, 0, 0);
        }
    }
    float blv[4], brv[4];
    #pragma unroll
    for (int c = 0; c < 4; ++c) { blv[c] = bL[c * 16 + arow]; brv[c] = bR[c * 16 + arow]; }
    __syncthreads();   // all waves done reading wpack

    // epilogue: a,b -> LDS only
    #pragma unroll
    for (int c = 0; c < 4; ++c) {
        #pragma unroll
        for (int reg = 0; reg < 4; ++reg) {
            int rl = w * 16 + kb * 4 + reg;
            int j  = c * 16 + arow;
            float lv = sig(acc[c][reg]     + blv[c]);
            float rv = sig(acc[c + 4][reg] + brv[c]);
            as_s[rl * 64 + j] = (_Float16)(lv * rv);
            bs_s[rl * 64 + j] = (_Float16)(1.0f - lv);
        }
    }
    __syncthreads();

    // fused chunk summary: 4 segments of 16 rows, then combine
    {
        float A = 1.f, B = 0.f;
        #pragma unroll 4
        for (int i = 0; i < 16; ++i) {
            int rl = w * 16 + i;
            if (t0 + rl < NF - 1) {
                float a = (float)as_s[rl * 64 + lane];
                float b = (float)bs_s[rl * 64 + lane];
                B = fmaf(a, B, b);
                A *= a;
            }
        }
        pA_s[w * 64 + lane] = A;
        pB_s[w * 64 + lane] = B;
    }
    __syncthreads();
    if (tid < 64) {
        float A = 1.f, B = 0.f;
        #pragma unroll
        for (int s2 = 0; s2 < 4; ++s2) {
            float pA = pA_s[s2 * 64 + tid];
            float pB = pB_s[s2 * 64 + tid];
            B = fmaf(pA, B, pB);
            A *= pA;
        }
        sA[tid * NC + blockIdx.x] = A;   // transposed -> K3 coalesced
        sB[tid * NC + blockIdx.x] = B;
    }
}

// ---------------------------------------------------------------- K3
__global__ __launch_bounds__(64)
void k3_scan(const float* __restrict__ sA, const float* __restrict__ sB,
             float* __restrict__ u0)
{
    const int j = blockIdx.x;
    const int lane = threadIdx.x;
    const int NG = (NC + 63) / 64;   // 123
    float cB = 0.f;
    float A = (lane < NC) ? sA[j * NC + lane] : 1.f;
    float B = (lane < NC) ? sB[j * NC + lane] : 0.f;
    for (int g = 0; g < NG; ++g) {
        int cn = (g + 1) * 64 + lane;
        float nA = 1.f, nB = 0.f;
        if (cn < NC) { nA = sA[j * NC + cn]; nB = sB[j * NC + cn]; }
        #pragma unroll
        for (int d = 1; d < 64; d <<= 1) {
            float pA = __shfl_up(A, d);
            float pB = __shfl_up(B, d);
            if (lane >= d) { B = fmaf(A, pB, B); A *= pA; }
        }
        float eA = __shfl_up(A, 1), eB = __shfl_up(B, 1);
        if (lane == 0) { eA = 1.f; eB = 0.f; }
        int cc = g * 64 + lane;
        if (cc < NC) u0[cc * M + j] = fmaf(eA, cB, eB);
        float tA = __shfl(A, 63), tB = __shfl(B, 63);
        cB = fmaf(tA, cB, tB);
        A = nA; B = nB;
    }
}

// ---------------------------------------------------------------- K4
// Block = 1 chunk. Recompute a,b (identical pipeline to K1), apply scan from
// u0, logits MFMA, write out. d_out is write-only here.
__global__ __launch_bounds__(256, 2)
void k4_fused(const float* __restrict__ X,
              const float* __restrict__ WL, const float* __restrict__ bL,
              const float* __restrict__ WR, const float* __restrict__ bR,
              const float* __restrict__ u0,
              const float* __restrict__ WLog, const float* __restrict__ bLog,
              float* __restrict__ out)
{
    __shared__ _Float16 wpack[16 * 128 * 8];   // 32 KiB
    __shared__ _Float16 x_s[4][16][136];       // 17 KiB
    __shared__ _Float16 wlog[8 * 64 * 8];      // 8 KiB
    __shared__ _Float16 z_s[64][80];           // 10 KiB (160B rows, 16B-aligned)
    _Float16* as_s = wpack;                    // [64][64] (reuse after MFMA)
    _Float16* bs_s = wpack + 64 * 64;          // [64][64]

    const int tid  = threadIdx.x;
    const int lane = tid & 63;
    const int w    = tid >> 6;
    const int t0   = blockIdx.x * CH;

    // pack W = [WL|WR] (identical to K1)
    #pragma unroll
    for (int f = 0; f < 16; ++f) {
        int flat = f * 1024 + tid * 4;
        int k = flat >> 7, col = flat & 127;
        float4 v;
        if (col < 64) v = *(const float4*)&WL[k * 64 + col];
        else          v = *(const float4*)&WR[k * 64 + (col - 64)];
        int kb = k >> 3, kj = k & 7;
        wpack[(kb * 128 + col + 0) * 8 + kj] = (_Float16)v.x;
        wpack[(kb * 128 + col + 1) * 8 + kj] = (_Float16)v.y;
        wpack[(kb * 128 + col + 2) * 8 + kj] = (_Float16)v.z;
        wpack[(kb * 128 + col + 3) * 8 + kj] = (_Float16)v.w;
    }
    // pack W_logit
    #pragma unroll
    for (int f = 0; f < 4; ++f) {
        int flat = f * 1024 + tid * 4;
        int k = flat >> 6, c = flat & 63;
        float4 v = *(const float4*)&WLog[flat];
        int kb = k >> 3, kj = k & 7;
        wlog[(kb * 64 + c + 0) * 8 + kj] = (_Float16)v.x;
        wlog[(kb * 64 + c + 1) * 8 + kj] = (_Float16)v.y;
        wlog[(kb * 64 + c + 2) * 8 + kj] = (_Float16)v.z;
        wlog[(kb * 64 + c + 3) * 8 + kj] = (_Float16)v.w;
    }
    // stage X rows (identical to K1)
    const int r0 = t0 + w * 16;
    #pragma unroll
    for (int it = 0; it < 8; ++it) {
        int flat = it * 256 + lane * 4;
        int r = flat >> 7, k = flat & 127;
        float4 v = make_float4(0.f, 0.f, 0.f, 0.f);
        if (r0 + r < NF) v = *(const float4*)&X[(r0 + r) * KIN + k];
        f16x4 h = { (_Float16)v.x, (_Float16)v.y, (_Float16)v.z, (_Float16)v.w };
        *(f16x4*)&x_s[w][r][k] = h;
    }
    __syncthreads();

    // MFMA (identical to K1)
    const int arow = lane & 15;
    const int kb   = lane >> 4;
    f32x4 acc[8];
    #pragma unroll
    for (int c = 0; c < 8; ++c) acc[c] = (f32x4){0.f, 0.f, 0.f, 0.f};
    #pragma unroll
    for (int s = 0; s < 4; ++s) {
        f16x8 af = *(const f16x8*)&x_s[w][arow][s * 32 + kb * 8];
        #pragma unroll
        for (int c = 0; c < 8; ++c) {
            f16x8 bf = *(const f16x8*)&wpack[((s * 4 + kb) * 128 + c * 16 + arow) * 8];
            acc[c] = __builtin_amdgcn_mfma_f32_16x16x32_f16(af, bf, acc[c], 0, 0, 0);
        }
    }
    float blv[4], brv[4];
    #pragma unroll
    for (int c = 0; c < 4; ++c) { blv[c] = bL[c * 16 + arow]; brv[c] = bR[c * 16 + arow]; }
    __syncthreads();

    // epilogue: a,b -> LDS (bitwise identical to K1's values)
    #pragma unroll
    for (int c = 0; c < 4; ++c) {
        #pragma unroll
        for (int reg = 0; reg < 4; ++reg) {
            int rl = w * 16 + kb * 4 + reg;
            int j  = c * 16 + arow;
            float lv = sig(acc[c][reg]     + blv[c]);
            float rv = sig(acc[c + 4][reg] + brv[c]);
            as_s[rl * 64 + j] = (_Float16)(lv * rv);
            bs_s[rl * 64 + j] = (_Float16)(1.0f - lv);
        }
    }
    __syncthreads();

    // apply scan within chunk: wave 0 only, column per lane
    if (tid < 64) {
        float u = u0[blockIdx.x * 64 + tid];
        #pragma unroll 4
        for (int i = 0; i < CH; ++i) {
            z_s[i][tid] = (_Float16)u;
            if (t0 + i < NF - 1) {
                float a = (float)as_s[i * 64 + tid];
                float b = (float)bs_s[i * 64 + tid];
                u = fmaf(a, u, b);
            }
        }
    }
    __syncthreads();

    // logits MFMA: wave w -> rows [w*16, w*16+16)
    float bv[4];
    #pragma unroll
    for (int c = 0; c < 4; ++c) bv[c] = bLog[c * 16 + arow];
    f32x4 acc2[4];
    #pragma unroll
    for (int ct = 0; ct < 4; ++ct) acc2[ct] = (f32x4){0.f, 0.f, 0.f, 0.f};
    #pragma unroll
    for (int ks = 0; ks < 2; ++ks) {
        f16x8 af = *(const f16x8*)&z_s[w * 16 + arow][ks * 32 + kb * 8];
        #pragma unroll
        for (int ct = 0; ct < 4; ++ct) {
            f16x8 bf = *(const f16x8*)&wlog[((ks * 4 + kb) * 64 + ct * 16 + arow) * 8];
            acc2[ct] = __builtin_amdgcn_mfma_f32_16x16x32_f16(af, bf, acc2[ct], 0, 0, 0);
        }
    }
    #pragma unroll
    for (int ct = 0; ct < 4; ++ct) {
        #pragma unroll
        for (int reg = 0; reg < 4; ++reg) {
            int t = t0 + w * 16 + kb * 4 + reg;
            if (t < NF) out[t * M + ct * 16 + arow] = acc2[ct][reg] + bv[ct];
        }
    }
}

// ---------------------------------------------------------------- host
extern "C" void kernel_launch(void* const* d_in, const int* in_sizes, int n_in,
                              void* d_out, int out_size, void* d_ws, size_t ws_size,
                              hipStream_t stream)
{
    const float* X    = (const float*)d_in[0];
    // d_in[1] = targets (unused)
    const float* WL   = (const float*)d_in[2];
    const float* bL   = (const float*)d_in[3];
    const float* WR   = (const float*)d_in[4];
    const float* bR   = (const float*)d_in[5];
    const float* WLog = (const float*)d_in[6];
    const float* bLog = (const float*)d_in[7];

    float* ws = (float*)d_ws;
    float* sA = ws;                 // 64*NC
    float* sB = sA + 64 * NC;       // 64*NC
    float* u0 = sB + 64 * NC;       // NC*64   (~6 MB total)

    k1_summary<<<NC, 256, 0, stream>>>(X, WL, bL, WR, bR, sA, sB);
    k3_scan<<<M, 64, 0, stream>>>(sA, sB, u0);
    k4_fused<<<NC, 256, 0, stream>>>(X, WL, bL, WR, bR, u0, WLog, bLog, (float*)d_out);
}

// Round 4
// 277.861 us; speedup vs baseline: 2.4866x; 1.8962x over previous
//
#include <hip/hip_runtime.h>
#include <hip/hip_fp16.h>

// DeductronCTC pipeline v4:
//   K0: pre-pack WL|WR and W_logit into MFMA fragment layout (f16) in ws.
//   K1: X -> fp16-MFMA -> sigmoid -> a,b (LDS) -> chunk summary -> sA,sB.
//   K3: 2-level scan of chunk summaries -> u0 (64 blocks x 4 waves).
//   K4: recompute a,b (identical MFMA), 4-wave parallel apply-scan,
//       fp16-MFMA logits GEMM -> out (write-only).
// Replay-safe: no buffer both read+written by a kernel, no aliasing.

constexpr int NF  = 500000;
constexpr int KIN = 128;
constexpr int M   = 64;
constexpr int CH  = 64;
constexpr int NC  = (NF + CH - 1) / CH;   // 7813
constexpr int NG  = (NC + 63) / 64;       // 123 groups in K3
constexpr int GPW = (NG + 3) / 4;         // 31 groups per wave in K3

typedef _Float16 f16x8 __attribute__((ext_vector_type(8)));
typedef _Float16 f16x4 __attribute__((ext_vector_type(4)));
typedef float    f32x4 __attribute__((ext_vector_type(4)));

__device__ __forceinline__ float sig(float x) { return 1.0f / (1.0f + __expf(-x)); }

// ---------------------------------------------------------------- K0
// Pack W=[WL|WR] (16384 halfs) and W_logit (4096 halfs) into frag layout:
// dst[(k>>3)*COLS + col)*8 + (k&7)]. 20 blocks x 256 threads, 4 elems each.
__global__ void k0_pack(const float* __restrict__ WL, const float* __restrict__ WR,
                        const float* __restrict__ WLog,
                        _Float16* __restrict__ wpre, _Float16* __restrict__ wlogpre)
{
    int flat = blockIdx.x * 1024 + threadIdx.x * 4;
    if (flat < 16384) {
        int k = flat >> 7, col = flat & 127;
        float4 v = (col < 64) ? *(const float4*)&WL[k * 64 + col]
                              : *(const float4*)&WR[k * 64 + (col - 64)];
        int kb = k >> 3, kj = k & 7;
        wpre[(kb * 128 + col + 0) * 8 + kj] = (_Float16)v.x;
        wpre[(kb * 128 + col + 1) * 8 + kj] = (_Float16)v.y;
        wpre[(kb * 128 + col + 2) * 8 + kj] = (_Float16)v.z;
        wpre[(kb * 128 + col + 3) * 8 + kj] = (_Float16)v.w;
    } else if (flat < 16384 + 4096) {
        int f2 = flat - 16384;
        int k = f2 >> 6, c = f2 & 63;
        float4 v = *(const float4*)&WLog[f2];
        int kb = k >> 3, kj = k & 7;
        wlogpre[(kb * 64 + c + 0) * 8 + kj] = (_Float16)v.x;
        wlogpre[(kb * 64 + c + 1) * 8 + kj] = (_Float16)v.y;
        wlogpre[(kb * 64 + c + 2) * 8 + kj] = (_Float16)v.z;
        wlogpre[(kb * 64 + c + 3) * 8 + kj] = (_Float16)v.w;
    }
}

// ---------------------------------------------------------------- K1
__global__ __launch_bounds__(256, 3)
void k1_summary(const float* __restrict__ X, const _Float16* __restrict__ wpre,
                const float* __restrict__ bL, const float* __restrict__ bR,
                float* __restrict__ sA, float* __restrict__ sB)
{
    __shared__ _Float16 wpack[16384];        // 32 KiB (region A)
    __shared__ _Float16 x_s[4][16][136];     // 17 KiB (region B)
    _Float16* as_s = wpack;                  // reuse after MFMA: [64][64]
    _Float16* bs_s = wpack + 4096;           // [64][64]
    float*    pA_s = (float*)(wpack + 8192); // [4][64]
    float*    pB_s = pA_s + 256;

    const int tid  = threadIdx.x;
    const int lane = tid & 63;
    const int w    = tid >> 6;
    const int t0   = blockIdx.x * CH;

    // stage prepacked W: contiguous 16B copies, conflict-free
    #pragma unroll
    for (int i = 0; i < 8; ++i) {
        int c16 = i * 256 + tid;
        *(f16x8*)&wpack[c16 * 8] = ((const f16x8*)wpre)[c16];
    }
    // stage this wave's 16 X rows (f32 -> f16)
    const int r0 = t0 + w * 16;
    #pragma unroll
    for (int it = 0; it < 8; ++it) {
        int flat = it * 256 + lane * 4;
        int r = flat >> 7, k = flat & 127;
        float4 v = make_float4(0.f, 0.f, 0.f, 0.f);
        if (r0 + r < NF) v = *(const float4*)&X[(r0 + r) * KIN + k];
        f16x4 h = { (_Float16)v.x, (_Float16)v.y, (_Float16)v.z, (_Float16)v.w };
        *(f16x4*)&x_s[w][r][k] = h;
    }
    __syncthreads();

    // MFMA: wave w -> rows [w*16, w*16+16) x 128 cols
    const int arow = lane & 15;
    const int kb   = lane >> 4;
    f32x4 acc[8];
    #pragma unroll
    for (int c = 0; c < 8; ++c) acc[c] = (f32x4){0.f, 0.f, 0.f, 0.f};
    #pragma unroll
    for (int s = 0; s < 4; ++s) {
        f16x8 af = *(const f16x8*)&x_s[w][arow][s * 32 + kb * 8];
        #pragma unroll
        for (int c = 0; c < 8; ++c) {
            f16x8 bf = *(const f16x8*)&wpack[((s * 4 + kb) * 128 + c * 16 + arow) * 8];
            acc[c] = __builtin_amdgcn_mfma_f32_16x16x32_f16(af, bf, acc[c], 0, 0, 0);
        }
    }
    float blv[4], brv[4];
    #pragma unroll
    for (int c = 0; c < 4; ++c) { blv[c] = bL[c * 16 + arow]; brv[c] = bR[c * 16 + arow]; }
    __syncthreads();   // wpack reads done before as/bs overwrite

    // epilogue: a,b -> LDS (own wave's 16-row slice)
    #pragma unroll
    for (int c = 0; c < 4; ++c) {
        #pragma unroll
        for (int reg = 0; reg < 4; ++reg) {
            int rl = w * 16 + kb * 4 + reg;
            int j  = c * 16 + arow;
            float lv = sig(acc[c][reg]     + blv[c]);
            float rv = sig(acc[c + 4][reg] + brv[c]);
            as_s[rl * 64 + j] = (_Float16)(lv * rv);
            bs_s[rl * 64 + j] = (_Float16)(1.0f - lv);
        }
    }
    // chunk summary: own slice (same-wave LDS order guarantees visibility)
    {
        float A = 1.f, B = 0.f;
        #pragma unroll 4
        for (int i = 0; i < 16; ++i) {
            int rl = w * 16 + i;
            if (t0 + rl < NF - 1) {
                float a = (float)as_s[rl * 64 + lane];
                float b = (float)bs_s[rl * 64 + lane];
                B = fmaf(a, B, b);
                A *= a;
            }
        }
        pA_s[w * 64 + lane] = A;
        pB_s[w * 64 + lane] = B;
    }
    __syncthreads();
    if (tid < 64) {
        float A = 1.f, B = 0.f;
        #pragma unroll
        for (int s2 = 0; s2 < 4; ++s2) {
            float pA = pA_s[s2 * 64 + tid];
            float pB = pB_s[s2 * 64 + tid];
            B = fmaf(pA, B, pB);
            A *= pA;
        }
        sA[tid * NC + blockIdx.x] = A;   // transposed -> K3 coalesced reads
        sB[tid * NC + blockIdx.x] = B;
    }
}

// ---------------------------------------------------------------- K3
// 64 blocks (one per column) x 4 waves. Wave w scans GPW groups with
// register-held exclusive prefixes; cross-wave carry via LDS.
__global__ __launch_bounds__(256)
void k3_scan(const float* __restrict__ sA, const float* __restrict__ sB,
             float* __restrict__ u0)
{
    __shared__ float tA_s[4], tB_s[4];
    const int j    = blockIdx.x;
    const int lane = threadIdx.x & 63;
    const int w    = threadIdx.x >> 6;

    float PA[GPW], PB[GPW];
    float cA = 1.f, cB = 0.f;            // wave-local running carry
    #pragma unroll
    for (int g = 0; g < GPW; ++g) {
        int c = (w * GPW + g) * 64 + lane;
        float A = 1.f, B = 0.f;
        if (c < NC) { A = sA[j * NC + c]; B = sB[j * NC + c]; }
        #pragma unroll
        for (int d = 1; d < 64; d <<= 1) {
            float pA = __shfl_up(A, d), pB = __shfl_up(B, d);
            if (lane >= d) { B = fmaf(A, pB, B); A *= pA; }
        }
        float eA = __shfl_up(A, 1), eB = __shfl_up(B, 1);
        if (lane == 0) { eA = 1.f; eB = 0.f; }
        PA[g] = eA * cA;                  // prefix-from-wave-start
        PB[g] = fmaf(eA, cB, eB);
        float tA = __shfl(A, 63), tB = __shfl(B, 63);
        cB = fmaf(tA, cB, tB);
        cA *= tA;
    }
    if (lane == 0) { tA_s[w] = cA; tB_s[w] = cB; }
    __syncthreads();
    float uw = 0.f;                       // z[0] = 0; compose waves < w
    for (int s2 = 0; s2 < w; ++s2) uw = fmaf(tA_s[s2], uw, tB_s[s2]);
    #pragma unroll
    for (int g = 0; g < GPW; ++g) {
        int c = (w * GPW + g) * 64 + lane;
        if (c < NC) u0[c * M + j] = fmaf(PA[g], uw, PB[g]);
    }
}

// ---------------------------------------------------------------- K4
__global__ __launch_bounds__(256, 3)
void k4_fused(const float* __restrict__ X, const _Float16* __restrict__ wpre,
              const _Float16* __restrict__ wlogpre,
              const float* __restrict__ bL, const float* __restrict__ bR,
              const float* __restrict__ u0,
              const float* __restrict__ bLog, float* __restrict__ out)
{
    __shared__ _Float16 wpack[16384];        // region A
    __shared__ _Float16 x_s[4][16][136];     // region B (x, then z overlay)
    _Float16* as_s = wpack;                  // [64][64] after MFMA
    _Float16* bs_s = wpack + 4096;
    _Float16* wlog = wpack + 8192;           // 4096 halfs
    float*    pA_s = (float*)(wpack + 12288);
    float*    pB_s = pA_s + 256;
    _Float16* z_s  = (_Float16*)x_s;         // [64][72] overlay

    const int tid  = threadIdx.x;
    const int lane = tid & 63;
    const int w    = tid >> 6;
    const int t0   = blockIdx.x * CH;

    #pragma unroll
    for (int i = 0; i < 8; ++i) {
        int c16 = i * 256 + tid;
        *(f16x8*)&wpack[c16 * 8] = ((const f16x8*)wpre)[c16];
    }
    const int r0 = t0 + w * 16;
    #pragma unroll
    for (int it = 0; it < 8; ++it) {
        int flat = it * 256 + lane * 4;
        int r = flat >> 7, k = flat & 127;
        float4 v = make_float4(0.f, 0.f, 0.f, 0.f);
        if (r0 + r < NF) v = *(const float4*)&X[(r0 + r) * KIN + k];
        f16x4 h = { (_Float16)v.x, (_Float16)v.y, (_Float16)v.z, (_Float16)v.w };
        *(f16x4*)&x_s[w][r][k] = h;
    }
    __syncthreads();

    // MFMA (identical to K1 -> bitwise-identical a,b)
    const int arow = lane & 15;
    const int kb   = lane >> 4;
    f32x4 acc[8];
    #pragma unroll
    for (int c = 0; c < 8; ++c) acc[c] = (f32x4){0.f, 0.f, 0.f, 0.f};
    #pragma unroll
    for (int s = 0; s < 4; ++s) {
        f16x8 af = *(const f16x8*)&x_s[w][arow][s * 32 + kb * 8];
        #pragma unroll
        for (int c = 0; c < 8; ++c) {
            f16x8 bf = *(const f16x8*)&wpack[((s * 4 + kb) * 128 + c * 16 + arow) * 8];
            acc[c] = __builtin_amdgcn_mfma_f32_16x16x32_f16(af, bf, acc[c], 0, 0, 0);
        }
    }
    float blv[4], brv[4];
    #pragma unroll
    for (int c = 0; c < 4; ++c) { blv[c] = bL[c * 16 + arow]; brv[c] = bR[c * 16 + arow]; }
    __syncthreads();   // wpack + x_s reads done before overlays

    // stage wlog (region A tail, disjoint from as/bs)
    #pragma unroll
    for (int i = 0; i < 2; ++i) {
        int c16 = i * 256 + tid;
        *(f16x8*)&wlog[c16 * 8] = ((const f16x8*)wlogpre)[c16];
    }
    // epilogue: a,b -> LDS (own wave's slice)
    #pragma unroll
    for (int c = 0; c < 4; ++c) {
        #pragma unroll
        for (int reg = 0; reg < 4; ++reg) {
            int rl = w * 16 + kb * 4 + reg;
            int j  = c * 16 + arow;
            float lv = sig(acc[c][reg]     + blv[c]);
            float rv = sig(acc[c + 4][reg] + brv[c]);
            as_s[rl * 64 + j] = (_Float16)(lv * rv);
            bs_s[rl * 64 + j] = (_Float16)(1.0f - lv);
        }
    }

    // apply-scan, 4-wave parallel. pass 1: own-slice summary
    {
        float A = 1.f, B = 0.f;
        #pragma unroll 4
        for (int i = 0; i < 16; ++i) {
            int rl = w * 16 + i;
            if (t0 + rl < NF - 1) {
                float a = (float)as_s[rl * 64 + lane];
                float b = (float)bs_s[rl * 64 + lane];
                B = fmaf(a, B, b);
                A *= a;
            }
        }
        pA_s[w * 64 + lane] = A;
        pB_s[w * 64 + lane] = B;
    }
    __syncthreads();
    // pass 2: compose prior wave summaries onto chunk-start state
    float u = u0[blockIdx.x * 64 + lane];
    for (int s2 = 0; s2 < w; ++s2)
        u = fmaf(pA_s[s2 * 64 + lane], u, pB_s[s2 * 64 + lane]);
    // pass 3: emit z for own slice
    #pragma unroll 4
    for (int i = 0; i < 16; ++i) {
        int rl = w * 16 + i;
        z_s[rl * 72 + lane] = (_Float16)u;
        if (t0 + rl < NF - 1) {
            float a = (float)as_s[rl * 64 + lane];
            float b = (float)bs_s[rl * 64 + lane];
            u = fmaf(a, u, b);
        }
    }
    __syncthreads();   // z + wlog ready

    // logits MFMA: wave w -> rows [w*16, w*16+16)
    float bv[4];
    #pragma unroll
    for (int c = 0; c < 4; ++c) bv[c] = bLog[c * 16 + arow];
    f32x4 acc2[4];
    #pragma unroll
    for (int ct = 0; ct < 4; ++ct) acc2[ct] = (f32x4){0.f, 0.f, 0.f, 0.f};
    #pragma unroll
    for (int ks = 0; ks < 2; ++ks) {
        f16x8 af = *(const f16x8*)&z_s[(w * 16 + arow) * 72 + ks * 32 + kb * 8];
        #pragma unroll
        for (int ct = 0; ct < 4; ++ct) {
            f16x8 bf = *(const f16x8*)&wlog[((ks * 4 + kb) * 64 + ct * 16 + arow) * 8];
            acc2[ct] = __builtin_amdgcn_mfma_f32_16x16x32_f16(af, bf, acc2[ct], 0, 0, 0);
        }
    }
    #pragma unroll
    for (int ct = 0; ct < 4; ++ct) {
        #pragma unroll
        for (int reg = 0; reg < 4; ++reg) {
            int t = t0 + w * 16 + kb * 4 + reg;
            if (t < NF) out[t * M + ct * 16 + arow] = acc2[ct][reg] + bv[ct];
        }
    }
}

// ---------------------------------------------------------------- host
extern "C" void kernel_launch(void* const* d_in, const int* in_sizes, int n_in,
                              void* d_out, int out_size, void* d_ws, size_t ws_size,
                              hipStream_t stream)
{
    const float* X    = (const float*)d_in[0];
    const float* WL   = (const float*)d_in[2];
    const float* bL   = (const float*)d_in[3];
    const float* WR   = (const float*)d_in[4];
    const float* bR   = (const float*)d_in[5];
    const float* WLog = (const float*)d_in[6];
    const float* bLog = (const float*)d_in[7];

    float* ws = (float*)d_ws;
    float* sA = ws;                         // 64*NC
    float* sB = sA + 64 * NC;               // 64*NC
    float* u0 = sB + 64 * NC;               // NC*64
    _Float16* wpre    = (_Float16*)(u0 + 64 * NC);  // 16384 halfs (16B-aligned)
    _Float16* wlogpre = wpre + 16384;               // 4096 halfs

    k0_pack<<<20, 256, 0, stream>>>(WL, WR, WLog, wpre, wlogpre);
    k1_summary<<<NC, 256, 0, stream>>>(X, wpre, bL, bR, sA, sB);
    k3_scan<<<M, 256, 0, stream>>>(sA, sB, u0);
    k4_fused<<<NC, 256, 0, stream>>>(X, wpre, wlogpre, bL, bR, u0, bLog, (float*)d_out);
}

// Round 5
// 246.401 us; speedup vs baseline: 2.8041x; 1.1277x over previous
//
#include <hip/hip_runtime.h>
#include <hip/hip_fp16.h>

// DeductronCTC pipeline v5 (register-resident, minimal LDS):
//   K0: pre-pack WL|WR and W_logit into MFMA fragment layout (f16) in ws.
//   K1: A-frags from global X (cvt in regs), B-frags from wpre (L1),
//       MFMA -> sigmoid -> a,b in REGISTERS -> shfl-composed chunk summary
//       -> sA,sB. LDS = 2 KB, 1 barrier.
//   K3: 2-level scan of chunk summaries -> u0.
//   K4: identical MFMA/a,b recompute, shfl scan + cross-wave compose, z in
//       LDS only for the logits MFMA A-frag, logits GEMM -> out. LDS 11 KB.
// Replay-safe: no buffer both read+written by a kernel, no aliasing.

constexpr int NF  = 500000;
constexpr int KIN = 128;
constexpr int M   = 64;
constexpr int CH  = 64;
constexpr int NC  = (NF + CH - 1) / CH;   // 7813
constexpr int NG  = (NC + 63) / 64;       // 123
constexpr int GPW = (NG + 3) / 4;         // 31

typedef _Float16 f16x8 __attribute__((ext_vector_type(8)));
typedef float    f32x4 __attribute__((ext_vector_type(4)));

__device__ __forceinline__ float sig(float x) { return 1.0f / (1.0f + __expf(-x)); }

// ---------------------------------------------------------------- K0
__global__ void k0_pack(const float* __restrict__ WL, const float* __restrict__ WR,
                        const float* __restrict__ WLog,
                        _Float16* __restrict__ wpre, _Float16* __restrict__ wlogpre)
{
    int flat = blockIdx.x * 1024 + threadIdx.x * 4;
    if (flat < 16384) {
        int k = flat >> 7, col = flat & 127;
        float4 v = (col < 64) ? *(const float4*)&WL[k * 64 + col]
                              : *(const float4*)&WR[k * 64 + (col - 64)];
        int kb = k >> 3, kj = k & 7;
        wpre[(kb * 128 + col + 0) * 8 + kj] = (_Float16)v.x;
        wpre[(kb * 128 + col + 1) * 8 + kj] = (_Float16)v.y;
        wpre[(kb * 128 + col + 2) * 8 + kj] = (_Float16)v.z;
        wpre[(kb * 128 + col + 3) * 8 + kj] = (_Float16)v.w;
    } else if (flat < 16384 + 4096) {
        int f2 = flat - 16384;
        int k = f2 >> 6, c = f2 & 63;
        float4 v = *(const float4*)&WLog[f2];
        int kb = k >> 3, kj = k & 7;
        wlogpre[(kb * 64 + c + 0) * 8 + kj] = (_Float16)v.x;
        wlogpre[(kb * 64 + c + 1) * 8 + kj] = (_Float16)v.y;
        wlogpre[(kb * 64 + c + 2) * 8 + kj] = (_Float16)v.z;
        wlogpre[(kb * 64 + c + 3) * 8 + kj] = (_Float16)v.w;
    }
}

// Shared MFMA + a,b recipe (identical code in K1/K4 -> identical values).
// Wave w covers rows [t0+w*16, +16) x 128 cols. Lane (kb=lane>>4, arow=lane&15)
// holds C rows kb*4+reg, cols c*16+arow (c<4: left, c>=4: right).
#define COMPUTE_AB()                                                          \
    f32x4 acc[8];                                                             \
    _Pragma("unroll")                                                         \
    for (int c = 0; c < 8; ++c) acc[c] = (f32x4){0.f, 0.f, 0.f, 0.f};         \
    {                                                                         \
        const int xrow = t0 + w * 16 + arow;                                  \
        const float* xp = X + (size_t)xrow * KIN;                             \
        const bool rowok = xrow < NF;                                         \
        _Pragma("unroll")                                                     \
        for (int s = 0; s < 4; ++s) {                                         \
            f32x4 v0 = (f32x4){0.f,0.f,0.f,0.f}, v1 = v0;                     \
            if (rowok) {                                                      \
                v0 = *(const f32x4*)&xp[s * 32 + kb * 8];                     \
                v1 = *(const f32x4*)&xp[s * 32 + kb * 8 + 4];                 \
            }                                                                 \
            f16x8 af = { (_Float16)v0.x, (_Float16)v0.y, (_Float16)v0.z,      \
                         (_Float16)v0.w, (_Float16)v1.x, (_Float16)v1.y,      \
                         (_Float16)v1.z, (_Float16)v1.w };                    \
            _Pragma("unroll")                                                 \
            for (int c = 0; c < 8; ++c) {                                     \
                f16x8 bf = *(const f16x8*)&wpre[((s*4+kb)*128 + c*16 + arow)*8]; \
                acc[c] = __builtin_amdgcn_mfma_f32_16x16x32_f16(af, bf, acc[c], 0, 0, 0); \
            }                                                                 \
        }                                                                     \
    }                                                                         \
    float a[4][4], b[4][4];                                                   \
    _Pragma("unroll")                                                         \
    for (int c = 0; c < 4; ++c) {                                             \
        float blv = bL[c * 16 + arow], brv = bR[c * 16 + arow];               \
        _Pragma("unroll")                                                     \
        for (int reg = 0; reg < 4; ++reg) {                                   \
            float lv = sig(acc[c][reg] + blv);                                \
            float rv = sig(acc[c + 4][reg] + brv);                            \
            a[c][reg] = lv * rv;                                              \
            b[c][reg] = 1.0f - lv;                                            \
        }                                                                     \
    }                                                                         \
    /* local 4-row compose + 2-step kb-group shfl scan (inclusive) */         \
    float Ai[4], Bi[4];                                                       \
    _Pragma("unroll")                                                         \
    for (int c = 0; c < 4; ++c) {                                             \
        float A = 1.f, B = 0.f;                                               \
        _Pragma("unroll")                                                     \
        for (int reg = 0; reg < 4; ++reg) {                                   \
            if (t0 + w * 16 + kb * 4 + reg < NF - 1) {                        \
                B = fmaf(a[c][reg], B, b[c][reg]);                            \
                A *= a[c][reg];                                               \
            }                                                                 \
        }                                                                     \
        Ai[c] = A; Bi[c] = B;                                                 \
    }                                                                         \
    _Pragma("unroll")                                                         \
    for (int d = 16; d < 64; d <<= 1) {                                       \
        _Pragma("unroll")                                                     \
        for (int c = 0; c < 4; ++c) {                                         \
            float pA = __shfl_up(Ai[c], d), pB = __shfl_up(Bi[c], d);         \
            if (lane >= d) { Bi[c] = fmaf(Ai[c], pB, Bi[c]); Ai[c] *= pA; }   \
        }                                                                     \
    }

// ---------------------------------------------------------------- K1
__global__ __launch_bounds__(256, 4)
void k1_summary(const float* __restrict__ X, const _Float16* __restrict__ wpre,
                const float* __restrict__ bL, const float* __restrict__ bR,
                float* __restrict__ sA, float* __restrict__ sB)
{
    __shared__ float pA_s[256], pB_s[256];
    const int tid = threadIdx.x, lane = tid & 63, w = tid >> 6;
    const int arow = lane & 15, kb = lane >> 4;
    const int t0 = blockIdx.x * CH;

    COMPUTE_AB();

    if (kb == 3) {   // wave-total (16 rows) per column
        #pragma unroll
        for (int c = 0; c < 4; ++c) {
            pA_s[w * 64 + c * 16 + arow] = Ai[c];
            pB_s[w * 64 + c * 16 + arow] = Bi[c];
        }
    }
    __syncthreads();
    if (tid < 64) {
        float At = 1.f, Bt = 0.f;
        #pragma unroll
        for (int s2 = 0; s2 < 4; ++s2) {
            float qa = pA_s[s2 * 64 + tid], qb = pB_s[s2 * 64 + tid];
            Bt = fmaf(qa, Bt, qb);
            At *= qa;
        }
        sA[tid * NC + blockIdx.x] = At;
        sB[tid * NC + blockIdx.x] = Bt;
    }
}

// ---------------------------------------------------------------- K3
__global__ __launch_bounds__(256)
void k3_scan(const float* __restrict__ sA, const float* __restrict__ sB,
             float* __restrict__ u0)
{
    __shared__ float tA_s[4], tB_s[4];
    const int j    = blockIdx.x;
    const int lane = threadIdx.x & 63;
    const int w    = threadIdx.x >> 6;

    float PA[GPW], PB[GPW];
    float cA = 1.f, cB = 0.f;
    #pragma unroll
    for (int g = 0; g < GPW; ++g) {
        int c = (w * GPW + g) * 64 + lane;
        float A = 1.f, B = 0.f;
        if (c < NC) { A = sA[j * NC + c]; B = sB[j * NC + c]; }
        #pragma unroll
        for (int d = 1; d < 64; d <<= 1) {
            float pA = __shfl_up(A, d), pB = __shfl_up(B, d);
            if (lane >= d) { B = fmaf(A, pB, B); A *= pA; }
        }
        float eA = __shfl_up(A, 1), eB = __shfl_up(B, 1);
        if (lane == 0) { eA = 1.f; eB = 0.f; }
        PA[g] = eA * cA;
        PB[g] = fmaf(eA, cB, eB);
        float tA = __shfl(A, 63), tB = __shfl(B, 63);
        cB = fmaf(tA, cB, tB);
        cA *= tA;
    }
    if (lane == 0) { tA_s[w] = cA; tB_s[w] = cB; }
    __syncthreads();
    float uw = 0.f;
    for (int s2 = 0; s2 < w; ++s2) uw = fmaf(tA_s[s2], uw, tB_s[s2]);
    #pragma unroll
    for (int g = 0; g < GPW; ++g) {
        int c = (w * GPW + g) * 64 + lane;
        if (c < NC) u0[c * M + j] = fmaf(PA[g], uw, PB[g]);
    }
}

// ---------------------------------------------------------------- K4
__global__ __launch_bounds__(256, 4)
void k4_fused(const float* __restrict__ X, const _Float16* __restrict__ wpre,
              const _Float16* __restrict__ wlogpre,
              const float* __restrict__ bL, const float* __restrict__ bR,
              const float* __restrict__ u0,
              const float* __restrict__ bLog, float* __restrict__ out)
{
    __shared__ float pA_s[256], pB_s[256];
    __shared__ _Float16 z_s[64 * 72];     // 9 KiB, pitch 72 halfs
    const int tid = threadIdx.x, lane = tid & 63, w = tid >> 6;
    const int arow = lane & 15, kb = lane >> 4;
    const int t0 = blockIdx.x * CH;

    COMPUTE_AB();

    // exclusive kb-prefix (state transform from wave start to lane's rows)
    float eA[4], eB[4];
    #pragma unroll
    for (int c = 0; c < 4; ++c) {
        eA[c] = __shfl_up(Ai[c], 16);
        eB[c] = __shfl_up(Bi[c], 16);
        if (kb == 0) { eA[c] = 1.f; eB[c] = 0.f; }
    }
    if (kb == 3) {
        #pragma unroll
        for (int c = 0; c < 4; ++c) {
            pA_s[w * 64 + c * 16 + arow] = Ai[c];
            pB_s[w * 64 + c * 16 + arow] = Bi[c];
        }
    }
    __syncthreads();

    // chunk-start state, composed through prior waves
    float u[4];
    #pragma unroll
    for (int c = 0; c < 4; ++c) u[c] = u0[blockIdx.x * 64 + c * 16 + arow];
    for (int s2 = 0; s2 < w; ++s2) {
        #pragma unroll
        for (int c = 0; c < 4; ++c) {
            float qa = pA_s[s2 * 64 + c * 16 + arow];
            float qb = pB_s[s2 * 64 + c * 16 + arow];
            u[c] = fmaf(qa, u[c], qb);
        }
    }
    // z for own rows (z_t = state BEFORE transform t), write to LDS
    #pragma unroll
    for (int c = 0; c < 4; ++c) {
        float uk = fmaf(eA[c], u[c], eB[c]);
        #pragma unroll
        for (int reg = 0; reg < 4; ++reg) {
            z_s[(w * 16 + kb * 4 + reg) * 72 + c * 16 + arow] = (_Float16)uk;
            if (t0 + w * 16 + kb * 4 + reg < NF - 1)
                uk = fmaf(a[c][reg], uk, b[c][reg]);
        }
    }
    __syncthreads();

    // logits MFMA: wave w -> rows [w*16, +16)
    f32x4 acc2[4];
    #pragma unroll
    for (int ct = 0; ct < 4; ++ct) acc2[ct] = (f32x4){0.f, 0.f, 0.f, 0.f};
    #pragma unroll
    for (int ks = 0; ks < 2; ++ks) {
        f16x8 af = *(const f16x8*)&z_s[(w * 16 + arow) * 72 + ks * 32 + kb * 8];
        #pragma unroll
        for (int ct = 0; ct < 4; ++ct) {
            f16x8 bf = *(const f16x8*)&wlogpre[((ks * 4 + kb) * 64 + ct * 16 + arow) * 8];
            acc2[ct] = __builtin_amdgcn_mfma_f32_16x16x32_f16(af, bf, acc2[ct], 0, 0, 0);
        }
    }
    #pragma unroll
    for (int ct = 0; ct < 4; ++ct) {
        float bv = bLog[ct * 16 + arow];
        #pragma unroll
        for (int reg = 0; reg < 4; ++reg) {
            int t = t0 + w * 16 + kb * 4 + reg;
            if (t < NF) out[t * M + ct * 16 + arow] = acc2[ct][reg] + bv;
        }
    }
}

// ---------------------------------------------------------------- host
extern "C" void kernel_launch(void* const* d_in, const int* in_sizes, int n_in,
                              void* d_out, int out_size, void* d_ws, size_t ws_size,
                              hipStream_t stream)
{
    const float* X    = (const float*)d_in[0];
    const float* WL   = (const float*)d_in[2];
    const float* bL   = (const float*)d_in[3];
    const float* WR   = (const float*)d_in[4];
    const float* bR   = (const float*)d_in[5];
    const float* WLog = (const float*)d_in[6];
    const float* bLog = (const float*)d_in[7];

    float* ws = (float*)d_ws;
    float* sA = ws;                         // 64*NC
    float* sB = sA + 64 * NC;               // 64*NC
    float* u0 = sB + 64 * NC;               // NC*64
    _Float16* wpre    = (_Float16*)(u0 + 64 * NC);  // 16384 halfs
    _Float16* wlogpre = wpre + 16384;               // 4096 halfs

    k0_pack<<<20, 256, 0, stream>>>(WL, WR, WLog, wpre, wlogpre);
    k1_summary<<<NC, 256, 0, stream>>>(X, wpre, bL, bR, sA, sB);
    k3_scan<<<M, 256, 0, stream>>>(sA, sB, u0);
    k4_fused<<<NC, 256, 0, stream>>>(X, wpre, wlogpre, bL, bR, u0, bLog, (float*)d_out);
}